// Round 7
// baseline (256.049 us; speedup 1.0000x reference)
//
#include <hip/hip_runtime.h>

// GNN NNConv, N=25000, E=50000, C=49, 3 live layers (layer 3 of ref is dead code).
// msg[e,o] = sum_k t[e,k]*U_k[src,o] + U_b[src,o];  U per NODE (GEMM).
// U stored as U[n][o][4] (k innermost) -> per-edge gather is ONE float4/lane.
// Root GEMV hoisted into dense kernels (Rt = h@root_w + cb, lanes 196..244).
// BN stats -> 8 replicated atomic slots, finalize recomputed by consumers
// (NO __threadfence: last-block protocols cost ~90ns/block device-wide).
// Dispatch-minimal: 8 dispatches, 0 memsets.
//   degscan(1 blk: LDS hist+scan, writes rowptr+cnt, zeroes st)
//   fuse2(scatter || h2u0) ; g0 ; u1 ; g1 ; u2 ; g2 ; fnorm

#define N 25000
#define E 50000
#define C 49
#define C2 196
#define SLOPE 0.01f
#define BPN 32            // nodes per block in dense kernels
#define GK 2              // nodes per wave in gathpre
#define NPB 8             // nodes per block in gathpre
#define NREP 8            // stat replicas (layer stride 1024 floats, replica stride 128)
#define HALF 12500        // histogram half-size (50KB int LDS)

__device__ __forceinline__ float leaky(float v) { return v > 0.f ? v : SLOPE * v; }
#define RFL(x) __builtin_amdgcn_readfirstlane(x)

// ---- single-block: deg histogram (2 LDS passes) + scan -> rowptr, cnt; zero st ----
__global__ __launch_bounds__(1024) void degscan_kernel(const int* __restrict__ ei,
                                                       int* __restrict__ rowptr,
                                                       int* __restrict__ cnt,
                                                       float* __restrict__ st) {
    __shared__ int sdeg[HALF + 44];
    __shared__ int wsum[16];
    __shared__ int carrys;
    int t = threadIdx.x, lane = t & 63, wv = t >> 6;
    if (t == 0) carrys = 0;
    for (int i = t; i < 3 * 1024; i += 1024) st[i] = 0.f;
#pragma unroll 1
    for (int half = 0; half < 2; half++) {
        int lo = half * HALF;
        for (int i = t; i < HALF; i += 1024) sdeg[i] = 0;
        __syncthreads();
        for (int e = t; e < E; e += 1024) {
            int d = ei[E + e] - lo;
            if ((unsigned)d < (unsigned)HALF) atomicAdd(&sdeg[d], 1);
        }
        __syncthreads();
        int base = t * 13;
        int loc[13];
        int run = 0;
#pragma unroll
        for (int i = 0; i < 13; i++) {
            loc[i] = run;
            int idx = base + i;
            run += (idx < HALF) ? sdeg[idx] : 0;
        }
        int inc = run;
#pragma unroll
        for (int s = 1; s < 64; s <<= 1) {
            int v = __shfl_up(inc, s, 64);
            if (lane >= s) inc += v;
        }
        if (lane == 63) wsum[wv] = inc;
        __syncthreads();
        if (t < 16) {
            int v = wsum[t];
#pragma unroll
            for (int s = 1; s < 16; s <<= 1) {
                int u = __shfl_up(v, s, 64);
                if (t >= s) v += u;
            }
            wsum[t] = v;
        }
        __syncthreads();
        int pbase = carrys + inc - run + (wv ? wsum[wv - 1] : 0);
#pragma unroll
        for (int i = 0; i < 13; i++) {
            int idx = base + i;
            int g = lo + idx;
            if (idx < HALF && g < N) {
                int v = pbase + loc[i];
                rowptr[g] = v;
                cnt[g] = v;
            }
        }
        __syncthreads();
        if (t == 0) carrys += wsum[15];
        __syncthreads();
    }
    if (t == 0) rowptr[N] = E;
}

// shared GEMM phase: hs[BPN][52] -> U[n][o*4+k] (t<196) and Rt[n][o]=h@rw+cb (t in [196,245))
__device__ __forceinline__ void gemm_phase(const float (*hs)[52], int base, int nv,
                                           const float* __restrict__ w2,
                                           const float* __restrict__ b2,
                                           const float* __restrict__ rw,
                                           const float* __restrict__ cb,
                                           float* __restrict__ U, float* __restrict__ Rt,
                                           int t) {
    if (t >= 245) return;
    int k = t / C, o = t % C;
    const float* Wp = (k < 3 ? w2 + k * (C * C) : (k == 3 ? b2 : rw)) + o;
    float bias = (k == 4) ? cb[o] : 0.f;
    float w[52];
#pragma unroll
    for (int i = 0; i < C; i++) w[i] = Wp[i * C];
    w[49] = w[50] = w[51] = 0.f;
#pragma unroll 2
    for (int n = 0; n < nv; n++) {
        float acc = bias;
#pragma unroll
        for (int i4 = 0; i4 < 13; i4++) {
            float4 hv = *reinterpret_cast<const float4*>(&hs[n][i4 * 4]);
            acc += hv.x * w[i4 * 4] + hv.y * w[i4 * 4 + 1] + hv.z * w[i4 * 4 + 2] +
                   hv.w * w[i4 * 4 + 3];
        }
        if (k < 4) U[(size_t)(base + n) * C2 + o * 4 + k] = acc;
        else Rt[(size_t)(base + n) * C + o] = acc;
    }
}

// fused dispatch: blocks [0,HB) = h2u0 (h GEMV + JK init + U0/Rt0);
//                 blocks [HB,..) = CSR scatter + edge-MLP (PK records, 3 layers)
__global__ __launch_bounds__(256) void fuse2_kernel(
    const float* __restrict__ x, const float* __restrict__ lw, const float* __restrict__ lb,
    const float* __restrict__ w2, const float* __restrict__ b2, const float* __restrict__ rw,
    const float* __restrict__ cb, const int* __restrict__ ei, const float* __restrict__ ea,
    const float* __restrict__ w1, const float* __restrict__ b1, int* __restrict__ cnt,
    float* __restrict__ PK, float* __restrict__ out, float* __restrict__ U,
    float* __restrict__ Rt, int HB) {
    __shared__ float xs[BPN][56];
    __shared__ float hs[BPN][52];
    int t = threadIdx.x;
    if ((int)blockIdx.x < HB) {
        int base = blockIdx.x * BPN;
        int nv = min(BPN, N - base);
        for (int e = t; e < nv * 56; e += 256) xs[e / 56][e % 56] = x[(size_t)base * 56 + e];
        for (int j = t; j < BPN * 3; j += 256) hs[j / 3][C + (j % 3)] = 0.f;
        __syncthreads();
        int r = t >> 6, c = t & 63;
        if (c < C) {
            float w[56];
#pragma unroll
            for (int i = 0; i < 56; i++) w[i] = lw[i * C + c];
            float bias = lb[c];
            for (int n = r; n < nv; n += 4) {
                float acc = bias;
#pragma unroll
                for (int i4 = 0; i4 < 14; i4++) {
                    float4 hv = *reinterpret_cast<const float4*>(&xs[n][i4 * 4]);
                    acc += hv.x * w[i4 * 4] + hv.y * w[i4 * 4 + 1] + hv.z * w[i4 * 4 + 2] +
                           hv.w * w[i4 * 4 + 3];
                }
                acc = leaky(acc);
                out[(size_t)(base + n) * C + c] = acc;
                hs[n][c] = acc;
            }
        }
        __syncthreads();
        gemm_phase(hs, base, nv, w2, b2, rw, cb, U, Rt, t);
    } else {
        int e = (blockIdx.x - HB) * 256 + t;
        if (e >= E) return;
        int s = ei[e], d = ei[E + e];
        int pos = atomicAdd(&cnt[d], 1);   // cnt pre-seeded with row starts
        float a[10];
#pragma unroll
        for (int j = 0; j < 10; j++) a[j] = ea[e * 10 + j];
#pragma unroll
        for (int l = 0; l < 3; l++) {
            float tk[3];
#pragma unroll
            for (int k = 0; k < 3; k++) {
                float acc = b1[l * 3 + k];
#pragma unroll
                for (int j = 0; j < 10; j++) acc += a[j] * w1[l * 30 + j * 3 + k];
                tk[k] = fmaxf(acc, 0.f);
            }
            float4 rec = make_float4(__int_as_float(s), tk[0], tk[1], tk[2]);
            *reinterpret_cast<float4*>(PK + ((size_t)l * E + pos) * 4) = rec;
        }
    }
}

// BN finalize (from raw replicated S/Q) + apply -> JK out + hs; then U, Rt
__global__ __launch_bounds__(256) void uni_kernel(
    const float* __restrict__ in, const float* __restrict__ stRaw,
    const float* __restrict__ gm, const float* __restrict__ bt,
    const float* __restrict__ w2, const float* __restrict__ b2,
    const float* __restrict__ rw, const float* __restrict__ cb,
    float* __restrict__ out, float* __restrict__ U, float* __restrict__ Rt) {
    __shared__ float hs[BPN][52];
    __shared__ float scl[64], sft[64];
    int t = threadIdx.x, base = blockIdx.x * BPN;
    int nv = min(BPN, N - base);
    if (t < C) {
        float S = 0.f, Q = 0.f;
#pragma unroll
        for (int r = 0; r < NREP; r++) {
            S += stRaw[r * 128 + t];
            Q += stRaw[r * 128 + 64 + t];
        }
        float mu = S * (1.0f / N);
        float var = Q * (1.0f / N) - mu * mu;
        float sc = rsqrtf(var + 1e-5f) * gm[t];
        scl[t] = sc;
        sft[t] = bt[t] - mu * sc;
    }
    for (int j = t; j < BPN * 3; j += 256) hs[j / 3][C + j % 3] = 0.f;
    __syncthreads();
    for (int e = t; e < nv * C; e += 256) {
        int n = e / C, i = e % C;
        float v = in[(size_t)base * C + e];
        v = leaky(v * scl[i] + sft[i]);
        out[(size_t)base * C + e] += v;
        hs[n][i] = v;
    }
    __syncthreads();
    gemm_phase(hs, base, nv, w2, b2, rw, cb, U, Rt, t);
}

// CSR gather (4-edge branchless quads) + Rt add => pre; per-block stats -> replicated slots
__global__ __launch_bounds__(256) void gathpre_kernel(
    const int* __restrict__ rowptr, const float* __restrict__ PK, const float* __restrict__ U,
    const float* __restrict__ Rt, float* __restrict__ pre, float* __restrict__ st) {
    __shared__ float red[8][64];
    int t = threadIdx.x, wv = t >> 6, c = t & 63;
    int n0 = blockIdx.x * NPB + wv * GK;
    float s = 0.f, q = 0.f;
    int nend = min(n0 + GK, N);
    const float4* PK4 = reinterpret_cast<const float4*>(PK);
    for (int n = n0; n < nend; n++) {
        int nu = RFL(n);
        int j0 = RFL(rowptr[nu]);
        int j1 = RFL(rowptr[nu + 1]);
        if (c < C) {
            float rr = Rt[(size_t)nu * C + c];
            float a0 = 0.f, a1 = 0.f, a2 = 0.f, a3 = 0.f;
            int jc = max(j1 - 1, j0);  // clamp target (deg=0 safe)
            int j = j0;
            do {
#define EDGE_TERM(K, AK)                                                          \
                {                                                                 \
                    int jj = min(j + K, jc);                                      \
                    float4 m = PK4[jj];                                           \
                    int sidx = RFL(__float_as_int(m.x));                          \
                    sidx = min(max(sidx, 0), N - 1);                              \
                    float4 u = *reinterpret_cast<const float4*>(                  \
                        U + (size_t)sidx * C2 + c * 4);                           \
                    float sc = (j + K < j1) ? 1.f : 0.f;                          \
                    AK += sc * (m.y * u.x + m.z * u.y + m.w * u.z + u.w);         \
                }
                EDGE_TERM(0, a0)
                EDGE_TERM(1, a1)
                EDGE_TERM(2, a2)
                EDGE_TERM(3, a3)
#undef EDGE_TERM
                j += 4;
            } while (j < j1);
            float inv = 1.0f / fmaxf((float)(j1 - j0), 1.0f);
            float acc = (a0 + a1 + a2 + a3) * inv + rr;
            pre[(size_t)nu * C + c] = acc;
            s += acc;
            q += acc * acc;
        }
    }
    red[wv][c] = s;
    red[4 + wv][c] = q;
    __syncthreads();
    if (t < C) {
        float* slot = st + (blockIdx.x & (NREP - 1)) * 128;
        float S = red[0][t] + red[1][t] + red[2][t] + red[3][t];
        float Q = red[4][t] + red[5][t] + red[6][t] + red[7][t];
        atomicAdd(&slot[t], S);
        atomicAdd(&slot[64 + t], Q);
    }
}

// last layer: out += leaky(pre*sc+sh); BN finalize per block from raw stats
__global__ __launch_bounds__(256) void fnorm_kernel(const float* __restrict__ pre,
                                                    const float* __restrict__ stRaw,
                                                    const float* __restrict__ gm,
                                                    const float* __restrict__ bt,
                                                    float* __restrict__ out) {
    __shared__ float scl[64], sft[64];
    int t = threadIdx.x;
    if (t < C) {
        float S = 0.f, Q = 0.f;
#pragma unroll
        for (int r = 0; r < NREP; r++) {
            S += stRaw[r * 128 + t];
            Q += stRaw[r * 128 + 64 + t];
        }
        float mu = S * (1.0f / N);
        float var = Q * (1.0f / N) - mu * mu;
        float sc = rsqrtf(var + 1e-5f) * gm[t];
        scl[t] = sc;
        sft[t] = bt[t] - mu * sc;
    }
    __syncthreads();
    for (int idx = blockIdx.x * 256 + t; idx < N * C; idx += gridDim.x * 256) {
        int c = idx % C;
        out[idx] += leaky(pre[idx] * scl[c] + sft[c]);
    }
}

extern "C" void kernel_launch(void* const* d_in, const int* in_sizes, int n_in,
                              void* d_out, int out_size, void* d_ws, size_t ws_size,
                              hipStream_t stream) {
    const float* x  = (const float*)d_in[0];
    const int* ei   = (const int*)d_in[1];
    const float* ea = (const float*)d_in[2];
    const float* lw = (const float*)d_in[3];
    const float* lb = (const float*)d_in[4];
    const float* w1 = (const float*)d_in[5];
    const float* b1 = (const float*)d_in[6];
    const float* w2 = (const float*)d_in[7];
    const float* b2 = (const float*)d_in[8];
    const float* rw = (const float*)d_in[9];
    const float* cb = (const float*)d_in[10];
    const float* gm = (const float*)d_in[11];
    const float* bt = (const float*)d_in[12];
    float* out = (float*)d_out;

    float* ws     = (float*)d_ws;
    int*   cnt    = (int*)ws;                 // N
    int*   rowptr = cnt + N;                  // N+1
    float* st     = (float*)(rowptr + N + 1); // 3*1024 (layer l at st+1024*l, NREP slots of 128)
    float* PK     = st + 3 * 1024;            // 3*E*4
    float* agg    = PK + (size_t)12 * E;      // N*C (pre)
    float* Rt     = agg + (size_t)N * C;      // N*C
    float* U      = Rt + (size_t)N * C;       // N*C2

    const int HB = (N + BPN - 1) / BPN;       // h2u0 blocks
    const int SB = (E + 255) / 256;           // scatter blocks
    const int GPB = (N + NPB - 1) / NPB;      // gathpre blocks

    degscan_kernel<<<1, 1024, 0, stream>>>(ei, rowptr, cnt, st);
    fuse2_kernel<<<HB + SB, 256, 0, stream>>>(x, lw, lb, w2, b2, rw, cb, ei, ea, w1, b1,
                                              cnt, PK, out, U, Rt, HB);
    for (int l = 0; l < 3; l++) {
        if (l > 0) {
            uni_kernel<<<HB, 256, 0, stream>>>(
                agg, st + (size_t)(l - 1) * 1024, gm + (l - 1) * C, bt + (l - 1) * C,
                w2 + (size_t)l * 3 * C * C, b2 + (size_t)l * C * C,
                rw + (size_t)l * C * C, cb + l * C, out, U, Rt);
        }
        gathpre_kernel<<<GPB, 256, 0, stream>>>(
            rowptr, PK + (size_t)l * E * 4, U, Rt, agg, st + (size_t)l * 1024);
    }
    fnorm_kernel<<<512, 256, 0, stream>>>(agg, st + 2 * 1024, gm + 2 * C, bt + 2 * C, out);
}

// Round 8
// 228.535 us; speedup vs baseline: 1.1204x; 1.1204x over previous
//
#include <hip/hip_runtime.h>

// GNN NNConv, N=25000, E=50000, C=49, 3 live layers (layer 3 of ref is dead code).
// msg[e,o] = sum_k t[e,k]*U_k[src,o] + U_b[src,o];  U per NODE (GEMM).
// U stored as U[n][o][4] (k innermost) -> per-edge gather is ONE float4/lane.
// Root GEMV hoisted into dense kernels (Rt = h@root_w + cb, lanes 196..244).
// BN stats -> 8 replicated atomic slots, finalize recomputed by consumers
// (NO __threadfence: last-block protocols cost ~90ns/block device-wide).
// Histogram lives on the WHOLE chip (r7 lesson: single-block degscan = 52us).
// 10 dispatches: memset(cnt); fuseA(deg || h2u0); scanseed(1 blk, LDS-staged);
//                scatter; g0; u1; g1; u2; g2; fnorm

#define N 25000
#define E 50000
#define C 49
#define C2 196
#define SLOPE 0.01f
#define BPN 32            // nodes per block in dense kernels
#define GK 2              // nodes per wave in gathpre
#define NPB 8             // nodes per block in gathpre
#define NREP 8            // stat replicas (layer stride 1024 floats, replica stride 128)

__device__ __forceinline__ float leaky(float v) { return v > 0.f ? v : SLOPE * v; }
#define RFL(x) __builtin_amdgcn_readfirstlane(x)

// shared GEMM phase: hs[BPN][52] -> U[n][o*4+k] (t<196) and Rt[n][o]=h@rw+cb (t in [196,245))
__device__ __forceinline__ void gemm_phase(const float (*hs)[52], int base, int nv,
                                           const float* __restrict__ w2,
                                           const float* __restrict__ b2,
                                           const float* __restrict__ rw,
                                           const float* __restrict__ cb,
                                           float* __restrict__ U, float* __restrict__ Rt,
                                           int t) {
    if (t >= 245) return;
    int k = t / C, o = t % C;
    const float* Wp = (k < 3 ? w2 + k * (C * C) : (k == 3 ? b2 : rw)) + o;
    float bias = (k == 4) ? cb[o] : 0.f;
    float w[52];
#pragma unroll
    for (int i = 0; i < C; i++) w[i] = Wp[i * C];
    w[49] = w[50] = w[51] = 0.f;
#pragma unroll 2
    for (int n = 0; n < nv; n++) {
        float acc = bias;
#pragma unroll
        for (int i4 = 0; i4 < 13; i4++) {
            float4 hv = *reinterpret_cast<const float4*>(&hs[n][i4 * 4]);
            acc += hv.x * w[i4 * 4] + hv.y * w[i4 * 4 + 1] + hv.z * w[i4 * 4 + 2] +
                   hv.w * w[i4 * 4 + 3];
        }
        if (k < 4) U[(size_t)(base + n) * C2 + o * 4 + k] = acc;
        else Rt[(size_t)(base + n) * C + o] = acc;
    }
}

// fused dispatch A: blocks [0,DB) = deg histogram (global atomics into cnt);
//                   blocks [DB,DB+HB) = h2u0 (h GEMV + JK init + U0/Rt0)
__global__ __launch_bounds__(256) void fuseA_kernel(
    const int* __restrict__ ei, int* __restrict__ cnt,
    const float* __restrict__ x, const float* __restrict__ lw, const float* __restrict__ lb,
    const float* __restrict__ w2, const float* __restrict__ b2, const float* __restrict__ rw,
    const float* __restrict__ cb, float* __restrict__ out, float* __restrict__ U,
    float* __restrict__ Rt, int DB) {
    __shared__ float xs[BPN][56];
    __shared__ float hs[BPN][52];
    int t = threadIdx.x;
    if ((int)blockIdx.x < DB) {
        int e = blockIdx.x * 256 + t;
        if (e < E) atomicAdd(&cnt[ei[E + e]], 1);
        return;
    }
    int base = (blockIdx.x - DB) * BPN;
    int nv = min(BPN, N - base);
    for (int e = t; e < nv * 56; e += 256) xs[e / 56][e % 56] = x[(size_t)base * 56 + e];
    for (int j = t; j < BPN * 3; j += 256) hs[j / 3][C + (j % 3)] = 0.f;
    __syncthreads();
    int r = t >> 6, c = t & 63;
    if (c < C) {
        float w[56];
#pragma unroll
        for (int i = 0; i < 56; i++) w[i] = lw[i * C + c];
        float bias = lb[c];
        for (int n = r; n < nv; n += 4) {
            float acc = bias;
#pragma unroll
            for (int i4 = 0; i4 < 14; i4++) {
                float4 hv = *reinterpret_cast<const float4*>(&xs[n][i4 * 4]);
                acc += hv.x * w[i4 * 4] + hv.y * w[i4 * 4 + 1] + hv.z * w[i4 * 4 + 2] +
                       hv.w * w[i4 * 4 + 3];
            }
            acc = leaky(acc);
            out[(size_t)(base + n) * C + c] = acc;
            hs[n][c] = acc;
        }
    }
    __syncthreads();
    gemm_phase(hs, base, nv, w2, b2, rw, cb, U, Rt, t);
}

// single block: LDS-staged exclusive scan of cnt -> rowptr; re-seed cnt; zero st
__global__ __launch_bounds__(1024) void scanseed_kernel(int* __restrict__ cnt,
                                                        int* __restrict__ rowptr,
                                                        float* __restrict__ st) {
    __shared__ int sl[N];
    __shared__ int wsum[16];
    int t = threadIdx.x, lane = t & 63, wv = t >> 6;
    for (int i = t; i < 3 * 1024; i += 1024) st[i] = 0.f;
    for (int i = t; i < N; i += 1024) sl[i] = cnt[i];
    __syncthreads();
    int base = t * 25;
    int loc[25];
    int run = 0;
#pragma unroll
    for (int i = 0; i < 25; i++) {
        loc[i] = run;
        int idx = base + i;
        run += (idx < N) ? sl[idx] : 0;
    }
    int inc = run;
#pragma unroll
    for (int s = 1; s < 64; s <<= 1) {
        int v = __shfl_up(inc, s, 64);
        if (lane >= s) inc += v;
    }
    if (lane == 63) wsum[wv] = inc;
    __syncthreads();
    if (t < 16) {
        int v = wsum[t];
#pragma unroll
        for (int s = 1; s < 16; s <<= 1) {
            int u = __shfl_up(v, s, 64);
            if (t >= s) v += u;
        }
        wsum[t] = v;
    }
    __syncthreads();
    int pbase = inc - run + (wv ? wsum[wv - 1] : 0);
#pragma unroll
    for (int i = 0; i < 25; i++) {
        int idx = base + i;
        if (idx < N) sl[idx] = pbase + loc[i];
    }
    __syncthreads();
    for (int i = t; i < N; i += 1024) {
        int v = sl[i];
        rowptr[i] = v;
        cnt[i] = v;
    }
    if (t == 0) rowptr[N] = E;
}

// CSR scatter + edge-MLP: PK[l][pos] = {src_as_float, t0, t1, t2}
__global__ void scatter_kernel(const int* __restrict__ ei, const float* __restrict__ ea,
                               const float* __restrict__ w1, const float* __restrict__ b1,
                               int* __restrict__ cnt, float* __restrict__ PK) {
    int e = blockIdx.x * 256 + threadIdx.x;
    if (e >= E) return;
    int s = ei[e], d = ei[E + e];
    int pos = atomicAdd(&cnt[d], 1);   // cnt pre-seeded with row starts
    float a[10];
#pragma unroll
    for (int j = 0; j < 10; j++) a[j] = ea[e * 10 + j];
#pragma unroll
    for (int l = 0; l < 3; l++) {
        float tk[3];
#pragma unroll
        for (int k = 0; k < 3; k++) {
            float acc = b1[l * 3 + k];
#pragma unroll
            for (int j = 0; j < 10; j++) acc += a[j] * w1[l * 30 + j * 3 + k];
            tk[k] = fmaxf(acc, 0.f);
        }
        float4 rec = make_float4(__int_as_float(s), tk[0], tk[1], tk[2]);
        *reinterpret_cast<float4*>(PK + ((size_t)l * E + pos) * 4) = rec;
    }
}

// BN finalize (from raw replicated S/Q) + apply -> JK out + hs; then U, Rt
__global__ __launch_bounds__(256) void uni_kernel(
    const float* __restrict__ in, const float* __restrict__ stRaw,
    const float* __restrict__ gm, const float* __restrict__ bt,
    const float* __restrict__ w2, const float* __restrict__ b2,
    const float* __restrict__ rw, const float* __restrict__ cb,
    float* __restrict__ out, float* __restrict__ U, float* __restrict__ Rt) {
    __shared__ float hs[BPN][52];
    __shared__ float scl[64], sft[64];
    int t = threadIdx.x, base = blockIdx.x * BPN;
    int nv = min(BPN, N - base);
    if (t < C) {
        float S = 0.f, Q = 0.f;
#pragma unroll
        for (int r = 0; r < NREP; r++) {
            S += stRaw[r * 128 + t];
            Q += stRaw[r * 128 + 64 + t];
        }
        float mu = S * (1.0f / N);
        float var = Q * (1.0f / N) - mu * mu;
        float sc = rsqrtf(var + 1e-5f) * gm[t];
        scl[t] = sc;
        sft[t] = bt[t] - mu * sc;
    }
    for (int j = t; j < BPN * 3; j += 256) hs[j / 3][C + j % 3] = 0.f;
    __syncthreads();
    for (int e = t; e < nv * C; e += 256) {
        int n = e / C, i = e % C;
        float v = in[(size_t)base * C + e];
        v = leaky(v * scl[i] + sft[i]);
        out[(size_t)base * C + e] += v;
        hs[n][i] = v;
    }
    __syncthreads();
    gemm_phase(hs, base, nv, w2, b2, rw, cb, U, Rt, t);
}

// CSR gather (4-edge branchless quads) + Rt add => pre; per-block stats -> replicated slots
__global__ __launch_bounds__(256) void gathpre_kernel(
    const int* __restrict__ rowptr, const float* __restrict__ PK, const float* __restrict__ U,
    const float* __restrict__ Rt, float* __restrict__ pre, float* __restrict__ st) {
    __shared__ float red[8][64];
    int t = threadIdx.x, wv = t >> 6, c = t & 63;
    int n0 = blockIdx.x * NPB + wv * GK;
    float s = 0.f, q = 0.f;
    int nend = min(n0 + GK, N);
    const float4* PK4 = reinterpret_cast<const float4*>(PK);
    for (int n = n0; n < nend; n++) {
        int nu = RFL(n);
        int j0 = RFL(rowptr[nu]);
        int j1 = RFL(rowptr[nu + 1]);
        if (c < C) {
            float rr = Rt[(size_t)nu * C + c];
            float a0 = 0.f, a1 = 0.f, a2 = 0.f, a3 = 0.f;
            int jc = max(j1 - 1, j0);  // clamp target (deg=0 safe)
            int j = j0;
            do {
#define EDGE_TERM(K, AK)                                                          \
                {                                                                 \
                    int jj = min(j + K, jc);                                      \
                    float4 m = PK4[jj];                                           \
                    int sidx = RFL(__float_as_int(m.x));                          \
                    sidx = min(max(sidx, 0), N - 1);                              \
                    float4 u = *reinterpret_cast<const float4*>(                  \
                        U + (size_t)sidx * C2 + c * 4);                           \
                    float sc = (j + K < j1) ? 1.f : 0.f;                          \
                    AK += sc * (m.y * u.x + m.z * u.y + m.w * u.z + u.w);         \
                }
                EDGE_TERM(0, a0)
                EDGE_TERM(1, a1)
                EDGE_TERM(2, a2)
                EDGE_TERM(3, a3)
#undef EDGE_TERM
                j += 4;
            } while (j < j1);
            float inv = 1.0f / fmaxf((float)(j1 - j0), 1.0f);
            float acc = (a0 + a1 + a2 + a3) * inv + rr;
            pre[(size_t)nu * C + c] = acc;
            s += acc;
            q += acc * acc;
        }
    }
    red[wv][c] = s;
    red[4 + wv][c] = q;
    __syncthreads();
    if (t < C) {
        float* slot = st + (blockIdx.x & (NREP - 1)) * 128;
        float S = red[0][t] + red[1][t] + red[2][t] + red[3][t];
        float Q = red[4][t] + red[5][t] + red[6][t] + red[7][t];
        atomicAdd(&slot[t], S);
        atomicAdd(&slot[64 + t], Q);
    }
}

// last layer: out += leaky(pre*sc+sh); BN finalize per block from raw stats
__global__ __launch_bounds__(256) void fnorm_kernel(const float* __restrict__ pre,
                                                    const float* __restrict__ stRaw,
                                                    const float* __restrict__ gm,
                                                    const float* __restrict__ bt,
                                                    float* __restrict__ out) {
    __shared__ float scl[64], sft[64];
    int t = threadIdx.x;
    if (t < C) {
        float S = 0.f, Q = 0.f;
#pragma unroll
        for (int r = 0; r < NREP; r++) {
            S += stRaw[r * 128 + t];
            Q += stRaw[r * 128 + 64 + t];
        }
        float mu = S * (1.0f / N);
        float var = Q * (1.0f / N) - mu * mu;
        float sc = rsqrtf(var + 1e-5f) * gm[t];
        scl[t] = sc;
        sft[t] = bt[t] - mu * sc;
    }
    __syncthreads();
    for (int idx = blockIdx.x * 256 + t; idx < N * C; idx += gridDim.x * 256) {
        int c = idx % C;
        out[idx] += leaky(pre[idx] * scl[c] + sft[c]);
    }
}

extern "C" void kernel_launch(void* const* d_in, const int* in_sizes, int n_in,
                              void* d_out, int out_size, void* d_ws, size_t ws_size,
                              hipStream_t stream) {
    const float* x  = (const float*)d_in[0];
    const int* ei   = (const int*)d_in[1];
    const float* ea = (const float*)d_in[2];
    const float* lw = (const float*)d_in[3];
    const float* lb = (const float*)d_in[4];
    const float* w1 = (const float*)d_in[5];
    const float* b1 = (const float*)d_in[6];
    const float* w2 = (const float*)d_in[7];
    const float* b2 = (const float*)d_in[8];
    const float* rw = (const float*)d_in[9];
    const float* cb = (const float*)d_in[10];
    const float* gm = (const float*)d_in[11];
    const float* bt = (const float*)d_in[12];
    float* out = (float*)d_out;

    float* ws     = (float*)d_ws;
    int*   cnt    = (int*)ws;                 // N
    int*   rowptr = cnt + N;                  // N+1
    float* st     = (float*)(rowptr + N + 1); // 3*1024 (layer l at st+1024*l, NREP slots of 128)
    float* PK     = st + 3 * 1024;            // 3*E*4
    float* agg    = PK + (size_t)12 * E;      // N*C (pre)
    float* Rt     = agg + (size_t)N * C;      // N*C
    float* U      = Rt + (size_t)N * C;       // N*C2

    const int DB = (E + 255) / 256;           // deg blocks
    const int HB = (N + BPN - 1) / BPN;       // h2u0 blocks
    const int GPB = (N + NPB - 1) / NPB;      // gathpre blocks

    hipMemsetAsync(cnt, 0, (size_t)N * sizeof(int), stream);
    fuseA_kernel<<<DB + HB, 256, 0, stream>>>(ei, cnt, x, lw, lb, w2, b2, rw, cb,
                                              out, U, Rt, DB);
    scanseed_kernel<<<1, 1024, 0, stream>>>(cnt, rowptr, st);
    scatter_kernel<<<DB, 256, 0, stream>>>(ei, ea, w1, b1, cnt, PK);
    for (int l = 0; l < 3; l++) {
        if (l > 0) {
            uni_kernel<<<HB, 256, 0, stream>>>(
                agg, st + (size_t)(l - 1) * 1024, gm + (l - 1) * C, bt + (l - 1) * C,
                w2 + (size_t)l * 3 * C * C, b2 + (size_t)l * C * C,
                rw + (size_t)l * C * C, cb + l * C, out, U, Rt);
        }
        gathpre_kernel<<<GPB, 256, 0, stream>>>(
            rowptr, PK + (size_t)l * E * 4, U, Rt, agg, st + (size_t)l * 1024);
    }
    fnorm_kernel<<<512, 256, 0, stream>>>(agg, st + 2 * 1024, gm + 2 * C, bt + 2 * C, out);
}